// Round 1
// baseline (276.516 us; speedup 1.0000x reference)
//
#include <hip/hip_runtime.h>
#include <math.h>

#define VOCAB 2048
#define EMB 256
#define MAXLEN 8
#define NBATCH 16
#define LAT 16
#define NG4 8192      // 4*VOCAB
#define CHUNK 128
#define NJCH 18       // 16 chunks of Wr (2048 rows) + 2 chunks of Wk (256 rows)
#define NUBLK 32      // 2048 units / 64 per block

// token = argmax_j ( j/2048 <= v && v <= (j+1)/2048 ), 0 if none.
// cumsum of uniform softmax is exactly k/2048 in fp32/fp64; v*2048 is exact
// (power-of-2 scale), so: first j = ceil(u)-1 (clamped), u = v*2048.
__device__ __forceinline__ int token_of(float v) {
    float u = v * 2048.0f;
    if (!(u >= 0.0f) || u > 2048.0f) return 0;   // v<0, v>1, or NaN
    int k = (int)ceilf(u) - 1;
    return k < 0 ? 0 : k;
}

__device__ __forceinline__ float sigmoidf_(float x) { return 1.0f / (1.0f + expf(-x)); }

// ---- Kernel A: gather X[t][b][:] = E[token(b,t)][:], zero h and c ----
__global__ void k_init(const float* __restrict__ ip, const float* __restrict__ E,
                       float* __restrict__ X, float* __restrict__ h, float* __restrict__ c) {
    int idx = blockIdx.x * 256 + threadIdx.x;   // 0..32767
    int t = idx >> 12;          // /(16*256)
    int b = (idx >> 8) & 15;
    int k = idx & 255;
    int tok = token_of(ip[b * LAT + t]);
    X[idx] = E[tok * EMB + k];
    h[idx] = 0.0f;
    c[idx] = 0.0f;
}

// ---- Kernel B: z-partials. grid = NUBLK * NJCH blocks of 256.
// block (ub, jc): units u = ub*64 + (tid&63); batch group bg = tid>>6 (4 batches).
// jc<16 -> Wr rows jc*128.., lhs=h ; jc>=16 -> Wk rows (jc-16)*128.., lhs=X[t].
__global__ __launch_bounds__(256) void k_gemm(
        const float* __restrict__ Wr, const float* __restrict__ Wk,
        const float* __restrict__ X, const float* __restrict__ h,
        float* __restrict__ zp, int t) {
    int bx = blockIdx.x;
    int ub = bx & (NUBLK - 1);
    int jc = bx >> 5;
    int tid = threadIdx.x;
    int ul = tid & 63;
    int bg = tid >> 6;

    __shared__ __align__(16) float sl[CHUNK][NBATCH];   // [j_local][batch]
    const float* lsrc; int ld; int j0; const float* W;
    if (jc < 16) { lsrc = h;                       ld = VOCAB; j0 = jc * CHUNK;        W = Wr; }
    else         { lsrc = X + t * NBATCH * EMB;    ld = EMB;   j0 = (jc - 16) * CHUNK; W = Wk; }

    for (int l = tid; l < CHUNK * NBATCH; l += 256) {
        int jl = l >> 4, bb = l & 15;
        sl[jl][bb] = lsrc[bb * ld + j0 + jl];
    }
    __syncthreads();

    int u = ub * 64 + ul;
    const float* wp = W + (size_t)j0 * NG4 + u;
    float acc[4][4];
    #pragma unroll
    for (int g = 0; g < 4; ++g)
        #pragma unroll
        for (int i = 0; i < 4; ++i) acc[g][i] = 0.0f;

    #pragma unroll 4
    for (int jl = 0; jl < CHUNK; ++jl) {
        const float* wrow = wp + (size_t)jl * NG4;
        float w0 = wrow[0];
        float w1 = wrow[2048];
        float w2 = wrow[4096];
        float w3 = wrow[6144];
        float4 hb = *(const float4*)&sl[jl][bg * 4];
        acc[0][0] += w0 * hb.x; acc[0][1] += w0 * hb.y; acc[0][2] += w0 * hb.z; acc[0][3] += w0 * hb.w;
        acc[1][0] += w1 * hb.x; acc[1][1] += w1 * hb.y; acc[1][2] += w1 * hb.z; acc[1][3] += w1 * hb.w;
        acc[2][0] += w2 * hb.x; acc[2][1] += w2 * hb.y; acc[2][2] += w2 * hb.z; acc[2][3] += w2 * hb.w;
        acc[3][0] += w3 * hb.x; acc[3][1] += w3 * hb.y; acc[3][2] += w3 * hb.z; acc[3][3] += w3 * hb.w;
    }

    #pragma unroll
    for (int g = 0; g < 4; ++g)
        #pragma unroll
        for (int i = 0; i < 4; ++i)
            zp[(size_t)((jc * 16) + (bg * 4 + i)) * NG4 + g * 2048 + u] = acc[g][i];
}

// ---- Kernel C: reduce partials + bias, gates, masked state update, record H[t] ----
__global__ void k_update(const float* __restrict__ zp, const float* __restrict__ bv,
                         const float* __restrict__ ip, float* __restrict__ h,
                         float* __restrict__ c, float* __restrict__ H, int t) {
    int idx = blockIdx.x * 256 + threadIdx.x;   // 0..32767 : (b,u)
    int b = idx >> 11;
    int u = idx & 2047;
    float zi = bv[u], zf = bv[2048 + u], zg = bv[4096 + u], zo = bv[6144 + u];
    #pragma unroll
    for (int jc = 0; jc < NJCH; ++jc) {
        const float* p = zp + (size_t)(jc * 16 + b) * NG4 + u;
        zi += p[0];
        zf += p[2048];
        zg += p[4096];
        zo += p[6144];
    }
    float co = c[idx], ho = h[idx];
    float cn = sigmoidf_(zf) * co + sigmoidf_(zi) * tanhf(zg);
    float hn = sigmoidf_(zo) * tanhf(cn);
    int tok = token_of(ip[b * LAT + t]);
    float hw = tok != 0 ? hn : ho;
    float cw = tok != 0 ? cn : co;
    h[idx] = hw;
    c[idx] = cw;
    H[(size_t)t * (NBATCH * VOCAB) + idx] = hw;
}

// ---- Kernel D: softmax of all 128 recorded h rows -> d_out[b][t][:] ----
__global__ __launch_bounds__(256) void k_softmax(const float* __restrict__ H,
                                                 float* __restrict__ out) {
    int r = blockIdx.x;          // r = t*16 + b
    int t = r >> 4, b = r & 15;
    int tid = threadIdx.x;
    const float* hr = H + (size_t)r * VOCAB;
    float v[8];
    float m = -1e30f;
    #pragma unroll
    for (int i = 0; i < 8; ++i) { v[i] = hr[tid + i * 256]; m = fmaxf(m, v[i]); }

    __shared__ float redm[4], reds[4];
    int wid = tid >> 6, lane = tid & 63;
    #pragma unroll
    for (int off = 32; off; off >>= 1) m = fmaxf(m, __shfl_down(m, off));
    if (lane == 0) redm[wid] = m;
    __syncthreads();
    m = fmaxf(fmaxf(redm[0], redm[1]), fmaxf(redm[2], redm[3]));

    float e[8];
    float s = 0.0f;
    #pragma unroll
    for (int i = 0; i < 8; ++i) { e[i] = expf(v[i] - m); s += e[i]; }
    #pragma unroll
    for (int off = 32; off; off >>= 1) s += __shfl_down(s, off);
    if (lane == 0) reds[wid] = s;
    __syncthreads();
    s = reds[0] + reds[1] + reds[2] + reds[3];

    float* o = out + ((size_t)b * MAXLEN + t) * VOCAB;
    #pragma unroll
    for (int i = 0; i < 8; ++i) o[tid + i * 256] = e[i] / s;
}

extern "C" void kernel_launch(void* const* d_in, const int* in_sizes, int n_in,
                              void* d_out, int out_size, void* d_ws, size_t ws_size,
                              hipStream_t stream) {
    const float* ip = (const float*)d_in[0];   // (16,16)
    const float* E  = (const float*)d_in[1];   // (2048,256)
    const float* Wk = (const float*)d_in[2];   // (256,8192)
    const float* Wr = (const float*)d_in[3];   // (2048,8192)
    const float* bv = (const float*)d_in[4];   // (8192,)

    float* ws = (float*)d_ws;
    float* X  = ws;             // 8*16*256      = 32768
    float* h  = X + 32768;      // 16*2048       = 32768
    float* c  = h + 32768;      // 16*2048       = 32768
    float* H  = c + 32768;      // 8*16*2048     = 262144
    float* zp = H + 262144;     // 18*16*8192    = 2359296  (~9 MB)

    k_init<<<128, 256, 0, stream>>>(ip, E, X, h, c);
    for (int t = 0; t < MAXLEN; ++t) {
        k_gemm<<<NUBLK * NJCH, 256, 0, stream>>>(Wr, Wk, X, h, zp, t);
        k_update<<<128, 256, 0, stream>>>(zp, bv, ip, h, c, H, t);
    }
    k_softmax<<<128, 256, 0, stream>>>(H, (float*)d_out);
}

// Round 2
// 201.090 us; speedup vs baseline: 1.3751x; 1.3751x over previous
//
#include <hip/hip_runtime.h>
#include <math.h>

#define VOCAB 2048
#define EMB 256
#define MAXLEN 8
#define NBATCH 16
#define LAT 16
#define NG4 8192      // 4*VOCAB
#define CHUNK 64
#define NJCH 36       // 32 chunks of Wr (2048 rows) + 4 chunks of Wk (256 rows)
#define UBLKN 16      // 2048 units / 128 per block

// token = argmax_j ( j/2048 <= v && v <= (j+1)/2048 ), 0 if none.
// cumsum of uniform softmax is exactly k/2048 in fp32; v*2048 is exact
// (power-of-2 scale), so: first j = ceil(u)-1 (clamped), u = v*2048.
__device__ __forceinline__ int token_of(float v) {
    float u = v * 2048.0f;
    if (!(u >= 0.0f) || u > 2048.0f) return 0;   // v<0, v>1, or NaN
    int k = (int)ceilf(u) - 1;
    return k < 0 ? 0 : k;
}

__device__ __forceinline__ float sigmoidf_(float x) { return 1.0f / (1.0f + expf(-x)); }

// ---- Kernel A: gather X[t][b][:] = E[token(b,t)][:], zero h and c ----
__global__ void k_init(const float* __restrict__ ip, const float* __restrict__ E,
                       float* __restrict__ X, float* __restrict__ h, float* __restrict__ c) {
    int idx = blockIdx.x * 256 + threadIdx.x;   // 0..32767
    int t = idx >> 12;
    int b = (idx >> 8) & 15;
    int k = idx & 255;
    int tok = token_of(ip[b * LAT + t]);
    X[idx] = E[tok * EMB + k];
    h[idx] = 0.0f;
    c[idx] = 0.0f;
}

// ---- Kernel B: z-partials with 16-batch weight reuse.
// grid = (NJCH - jc0) * UBLKN blocks of 256.
// block (jc, ub): wave g = tid>>6 owns gate g; lane covers u = ub*128 + lane*2.
// Each thread: load float2 of W row, FMA against all 16 batches (LDS broadcast).
__global__ __launch_bounds__(256) void k_gemm(
        const float* __restrict__ Wr, const float* __restrict__ Wk,
        const float* __restrict__ X, const float* __restrict__ h,
        float* __restrict__ zp, int t, int jc0) {
    int bx = blockIdx.x;
    int ub = bx & (UBLKN - 1);
    int jc = jc0 + (bx >> 4);
    int tid = threadIdx.x;
    int g = tid >> 6;
    int lane = tid & 63;

    __shared__ __align__(16) float sh[CHUNK][NBATCH];   // [j_local][batch]

    const float* lsrc; int ld; int j0; const float* W;
    if (jc < 32) { lsrc = h;                       ld = VOCAB; j0 = jc * CHUNK;        W = Wr; }
    else         { lsrc = X + t * NBATCH * EMB;    ld = EMB;   j0 = (jc - 32) * CHUNK; W = Wk; }

    // stage lhs: thread reads float4 along j (coalesced), scatters to sh[j][b]
    {
        int bb = tid >> 4;          // 0..15
        int jl = (tid & 15) * 4;    // 0..60
        float4 v = *(const float4*)&lsrc[bb * ld + j0 + jl];
        sh[jl + 0][bb] = v.x;
        sh[jl + 1][bb] = v.y;
        sh[jl + 2][bb] = v.z;
        sh[jl + 3][bb] = v.w;
    }
    __syncthreads();

    int u = ub * 128 + lane * 2;
    const float* wp = W + (size_t)j0 * NG4 + g * 2048 + u;

    float acc[NBATCH][2];
    #pragma unroll
    for (int b = 0; b < NBATCH; ++b) { acc[b][0] = 0.0f; acc[b][1] = 0.0f; }

    #pragma unroll 4
    for (int jl = 0; jl < CHUNK; ++jl) {
        float2 w = *(const float2*)(wp + (size_t)jl * NG4);
        float hb[NBATCH];
        #pragma unroll
        for (int q = 0; q < 4; ++q) {
            float4 v = *((const float4*)&sh[jl][0] + q);   // same addr all lanes: broadcast
            hb[q * 4 + 0] = v.x; hb[q * 4 + 1] = v.y;
            hb[q * 4 + 2] = v.z; hb[q * 4 + 3] = v.w;
        }
        #pragma unroll
        for (int b = 0; b < NBATCH; ++b) {
            acc[b][0] = fmaf(w.x, hb[b], acc[b][0]);
            acc[b][1] = fmaf(w.y, hb[b], acc[b][1]);
        }
    }

    #pragma unroll
    for (int b = 0; b < NBATCH; ++b) {
        *(float2*)&zp[(size_t)(jc * NBATCH + b) * NG4 + g * 2048 + u] =
            make_float2(acc[b][0], acc[b][1]);
    }
}

// ---- Kernel C: reduce partials + bias, gates, masked state update, record H[t].
// grid = 128 blocks x 1024 threads: block (b, ug); thread (g, ul).
__global__ __launch_bounds__(1024) void k_update(
        const float* __restrict__ zp, const float* __restrict__ bv,
        const float* __restrict__ ip, float* __restrict__ h,
        float* __restrict__ c, float* __restrict__ H, int t, int jc0) {
    int b  = blockIdx.x >> 3;
    int ug = blockIdx.x & 7;
    int g  = threadIdx.x >> 8;
    int ul = threadIdx.x & 255;
    int u  = ug * 256 + ul;

    float z = bv[g * 2048 + u];
    const float* p = zp + (size_t)g * 2048 + u + (size_t)b * NG4;
    if (jc0 == 0) {
        #pragma unroll
        for (int jc = 0; jc < NJCH; ++jc) z += p[(size_t)jc * NBATCH * NG4];
    } else {
        #pragma unroll
        for (int jc = 32; jc < NJCH; ++jc) z += p[(size_t)jc * NBATCH * NG4];
    }

    __shared__ float sz[4][256];
    sz[g][ul] = z;
    __syncthreads();

    if (g == 0) {
        float zi = sz[0][ul], zf = sz[1][ul], zg = sz[2][ul], zo = sz[3][ul];
        int idx = b * VOCAB + u;
        float co = c[idx], ho = h[idx];
        float cn = sigmoidf_(zf) * co + sigmoidf_(zi) * tanhf(zg);
        float hn = sigmoidf_(zo) * tanhf(cn);
        int tok = token_of(ip[b * LAT + t]);
        float hw = tok != 0 ? hn : ho;
        float cw = tok != 0 ? cn : co;
        h[idx] = hw;
        c[idx] = cw;
        H[(size_t)t * (NBATCH * VOCAB) + idx] = hw;
    }
}

// ---- Kernel D: softmax of all 128 recorded h rows -> d_out[b][t][:] ----
__global__ __launch_bounds__(256) void k_softmax(const float* __restrict__ H,
                                                 float* __restrict__ out) {
    int r = blockIdx.x;          // r = t*16 + b
    int t = r >> 4, b = r & 15;
    int tid = threadIdx.x;
    const float* hr = H + (size_t)r * VOCAB;
    float v[8];
    float m = -1e30f;
    #pragma unroll
    for (int i = 0; i < 8; ++i) { v[i] = hr[tid + i * 256]; m = fmaxf(m, v[i]); }

    __shared__ float redm[4], reds[4];
    int wid = tid >> 6, lane = tid & 63;
    #pragma unroll
    for (int off = 32; off; off >>= 1) m = fmaxf(m, __shfl_down(m, off));
    if (lane == 0) redm[wid] = m;
    __syncthreads();
    m = fmaxf(fmaxf(redm[0], redm[1]), fmaxf(redm[2], redm[3]));

    float e[8];
    float s = 0.0f;
    #pragma unroll
    for (int i = 0; i < 8; ++i) { e[i] = expf(v[i] - m); s += e[i]; }
    #pragma unroll
    for (int off = 32; off; off >>= 1) s += __shfl_down(s, off);
    if (lane == 0) reds[wid] = s;
    __syncthreads();
    s = reds[0] + reds[1] + reds[2] + reds[3];

    float* o = out + ((size_t)b * MAXLEN + t) * VOCAB;
    #pragma unroll
    for (int i = 0; i < 8; ++i) o[tid + i * 256] = e[i] / s;
}

extern "C" void kernel_launch(void* const* d_in, const int* in_sizes, int n_in,
                              void* d_out, int out_size, void* d_ws, size_t ws_size,
                              hipStream_t stream) {
    const float* ip = (const float*)d_in[0];   // (16,16)
    const float* E  = (const float*)d_in[1];   // (2048,256)
    const float* Wk = (const float*)d_in[2];   // (256,8192)
    const float* Wr = (const float*)d_in[3];   // (2048,8192)
    const float* bv = (const float*)d_in[4];   // (8192,)

    float* ws = (float*)d_ws;
    float* X  = ws;             // 8*16*256      = 32768
    float* h  = X + 32768;      // 16*2048       = 32768
    float* c  = h + 32768;      // 16*2048       = 32768
    float* H  = c + 32768;      // 8*16*2048     = 262144
    float* zp = H + 262144;     // 36*16*8192   ~= 18.9 MB

    k_init<<<128, 256, 0, stream>>>(ip, E, X, h, c);
    for (int t = 0; t < MAXLEN; ++t) {
        int jc0 = (t == 0) ? 32 : 0;   // h==0 at t=0: skip all Wr chunks
        k_gemm<<<(NJCH - jc0) * UBLKN, 256, 0, stream>>>(Wr, Wk, X, h, zp, t, jc0);
        k_update<<<128, 1024, 0, stream>>>(zp, bv, ip, h, c, H, t, jc0);
    }
    k_softmax<<<128, 256, 0, stream>>>(H, (float*)d_out);
}